// Round 6
// baseline (75.537 us; speedup 1.0000x reference)
//
#include <hip/hip_runtime.h>

// PatchQuantumGenerator, round 6: fused, fully wave-local build.
// Block = 128 batches x 4 generators (wave wv owns g=wv).
// Each wave builds its own M_g = P*U (16x32 complex) in LDS with gates
// right-multiplied in reverse circuit order (algebra verified r5), using
// ONLY in-wave ordering (lgkmcnt drain + sched barrier) -- no cross-wave
// __syncthreads in the build. One __syncthreads total (sincos staging).
// Output: block writes one contiguous 32KB region (full cache lines).

#define NGEN 4
#define NLAY 4
#define NQ   5

typedef _Float16 half8 __attribute__((ext_vector_type(8)));
typedef float    f32x4 __attribute__((ext_vector_type(4)));

// In-wave LDS ordering: drain LDS ops, forbid compiler reordering.
// Cross-lane RAW within one wave is safe after lgkmcnt(0) (DS ops of a
// wave complete in order; lanes of a wave execute in lockstep).
#define WAVE_SYNC()                                                  \
    do {                                                             \
        __builtin_amdgcn_wave_barrier();                             \
        asm volatile("s_waitcnt lgkmcnt(0)" ::: "memory");           \
        __builtin_amdgcn_wave_barrier();                             \
    } while (0)

__global__ __launch_bounds__(256) void pqg_fused(
    const float* __restrict__ x,      // [B,5]
    const float* __restrict__ wts,    // [4,4,5,3]
    float* __restrict__ out)          // [B,64]
{
    __shared__ float gm[NGEN][NLAY * NQ * 8];
    __shared__ float Mr[NGEN][16 * 33];
    __shared__ float Mi[NGEN][16 * 33];
    __shared__ __align__(16) _Float16 afr[NGEN][512];
    __shared__ __align__(16) _Float16 afi[NGEN][512];
    __shared__ float scC[640];
    __shared__ float scS[640];

    const int t    = threadIdx.x;
    const int lane = t & 63;
    const int g    = t >> 6;              // wave index == generator
    const int b0   = blockIdx.x * 128;

    // ---- Sincos staging for the block's 128 batches (640 pairs).
    // Threads 0..159: one float4 of x each (coalesced, 16B-aligned).
    if (t < 160) {
        const float4 v = ((const float4*)(x + (size_t)b0 * 5))[t];
        scS[4 * t + 0] = __sinf(0.5f * v.x);  scC[4 * t + 0] = __cosf(0.5f * v.x);
        scS[4 * t + 1] = __sinf(0.5f * v.y);  scC[4 * t + 1] = __cosf(0.5f * v.y);
        scS[4 * t + 2] = __sinf(0.5f * v.z);  scC[4 * t + 2] = __cosf(0.5f * v.z);
        scS[4 * t + 3] = __sinf(0.5f * v.w);  scC[4 * t + 3] = __cosf(0.5f * v.w);
    }

    // ---- Gate matrices for this wave's g (lanes 0..19).
    // Rot = RZ(omega) RY(theta) RZ(phi); verified r1-r5.
    if (lane < NLAY * NQ) {
        const float* wp = wts + (g * (NLAY * NQ) + lane) * 3;
        const float phi = wp[0], theta = wp[1], omega = wp[2];
        const float a = 0.5f * (phi + omega);
        const float bb = 0.5f * (phi - omega);
        const float h = 0.5f * theta;
        const float sa = __sinf(a), ca = __cosf(a);
        const float sb = __sinf(bb), cb = __cosf(bb);
        const float st = __sinf(h), ct = __cosf(h);
        float* m = &gm[g][lane * 8];
        m[0] =  ca * ct;  m[1] = -sa * ct;   // u00
        m[2] = -cb * st;  m[3] = -sb * st;   // u01
        m[4] =  cb * st;  m[5] = -sb * st;   // u10
        m[6] =  ca * ct;  m[7] =  sa * ct;   // u11
    }

    // ---- M init: M = P (rows 0..15 of identity), stride 33.
#pragma unroll
    for (int h = 0; h < 8; ++h) {
        const int idx = h * 64 + lane;     // 0..511
        const int r = idx >> 5, c = idx & 31;
        Mr[g][r * 33 + c] = (r == c) ? 1.0f : 0.0f;
        Mi[g][r * 33 + c] = 0.0f;
    }
    WAVE_SYNC();

    const int p  = lane & 15;              // pair index 0..15
    const int rl = lane >> 4;              // row group 0..3

    // ---- Build M = P*U, gates in REVERSE circuit order (verified r5).
#pragma clang loop unroll(disable)
    for (int l = NLAY - 1; l >= 0; --l) {
        // CNOT group of layer l: column gather new[.,c] = old[.,sigma(c)],
        // sigma = apply q ascending: if (v & cb_q) v ^= tb_q.
        {
            int v0 = p, v1 = p + 16;
#pragma unroll
            for (int q = 0; q < NQ; ++q) {
                const int cb = 16 >> q;
                int tq = q + l + 1; if (tq >= NQ) tq -= NQ;
                const int tb = 16 >> tq;
                if (v0 & cb) v0 ^= tb;
                if (v1 & cb) v1 ^= tb;
            }
            float tr[8], ti[8];
#pragma unroll
            for (int r = 0; r < 4; ++r) {
                const int row = r * 4 + rl;
                tr[2 * r + 0] = Mr[g][row * 33 + v0];
                ti[2 * r + 0] = Mi[g][row * 33 + v0];
                tr[2 * r + 1] = Mr[g][row * 33 + v1];
                ti[2 * r + 1] = Mi[g][row * 33 + v1];
            }
            WAVE_SYNC();
#pragma unroll
            for (int r = 0; r < 4; ++r) {
                const int row = r * 4 + rl;
                Mr[g][row * 33 + p]      = tr[2 * r + 0];
                Mi[g][row * 33 + p]      = ti[2 * r + 0];
                Mr[g][row * 33 + p + 16] = tr[2 * r + 1];
                Mi[g][row * 33 + p + 16] = ti[2 * r + 1];
            }
            WAVE_SYNC();
        }
        // Rot gates of layer l, reverse order q=4..0. Right-mult:
        // col_i <- u00*col_i + u10*col_j ; col_j <- u01*col_i + u11*col_j.
#pragma clang loop unroll(disable)
        for (int q = NQ - 1; q >= 0; --q) {
            const float* m = &gm[g][(l * NQ + q) * 8];
            const float u00r = m[0], u00i = m[1], u01r = m[2], u01i = m[3];
            const float u10r = m[4], u10i = m[5], u11r = m[6], u11i = m[7];
            const int sb = 16 >> q;
            const int lowm = sb - 1;
            const int i = ((p & ~lowm) << 1) | (p & lowm);
            const int j = i | sb;
#pragma unroll
            for (int r = 0; r < 4; ++r) {
                const int row = r * 4 + rl;
                const int ii = row * 33 + i, jj = row * 33 + j;
                const float ar = Mr[g][ii], ai = Mi[g][ii];
                const float br = Mr[g][jj], bi = Mi[g][jj];
                Mr[g][ii] = u00r * ar - u00i * ai + u10r * br - u10i * bi;
                Mi[g][ii] = u00r * ai + u00i * ar + u10r * bi + u10i * br;
                Mr[g][jj] = u01r * ar - u01i * ai + u11r * br - u11i * bi;
                Mi[g][jj] = u01r * ai + u01i * ar + u11r * bi + u11i * br;
            }
            WAVE_SYNC();
        }
    }

    // ---- Emit f16 A-fragments (wave-local): (m,k) -> lane (k>>3)*16+m, reg k&7.
#pragma unroll
    for (int h = 0; h < 8; ++h) {
        const int idx = h * 64 + lane;     // 0..511
        const int k = idx >> 4, m = idx & 15;
        const int L = (k >> 3) * 16 + m;
        const int jj = k & 7;
        afr[g][L * 8 + jj] = (_Float16)Mr[g][m * 33 + k];
        afi[g][L * 8 + jj] = (_Float16)Mi[g][m * 33 + k];
    }

    // One real barrier: covers the shared sincos staging (and our emit).
    __syncthreads();

    // ---- GEMM: wave = its g, 8 tiles x 16 batches = 128 batches.
    const int quad = lane >> 4;
    const int n    = lane & 15;

    const half8 Ar = *(const half8*)&afr[g][lane * 8];
    const half8 Ai = *(const half8*)&afi[g][lane * 8];

#pragma unroll
    for (int t8 = 0; t8 < 8; ++t8) {
        const int bl = t8 * 16 + n;
        const int b  = b0 + bl;
        const float* C = &scC[bl * 5];
        const float* S = &scS[bl * 5];

        // B-frag bit-map (verified r2): k=quad*8+j; quad&2->q0, quad&1->q1,
        // j&4->q2, j&2->q3, j&1->q4.
        const float f01 = ((quad & 2) ? S[0] : C[0]) * ((quad & 1) ? S[1] : C[1]);
        const float a0 = f01 * C[2], a1 = f01 * S[2];
        const float b00 = a0 * C[3], b01 = a0 * S[3];
        const float b10 = a1 * C[3], b11 = a1 * S[3];

        half8 Bf;
        Bf[0] = (_Float16)(b00 * C[4]);  Bf[1] = (_Float16)(b00 * S[4]);
        Bf[2] = (_Float16)(b01 * C[4]);  Bf[3] = (_Float16)(b01 * S[4]);
        Bf[4] = (_Float16)(b10 * C[4]);  Bf[5] = (_Float16)(b10 * S[4]);
        Bf[6] = (_Float16)(b11 * C[4]);  Bf[7] = (_Float16)(b11 * S[4]);

        f32x4 accR = {0.f, 0.f, 0.f, 0.f};
        f32x4 accI = {0.f, 0.f, 0.f, 0.f};
        accR = __builtin_amdgcn_mfma_f32_16x16x32_f16(Ar, Bf, accR, 0, 0, 0);
        accI = __builtin_amdgcn_mfma_f32_16x16x32_f16(Ai, Bf, accI, 0, 0, 0);

        // C/D: col = lane&15 (batch), row = quad*4 + reg (output k).
        const float p0 = accR[0] * accR[0] + accI[0] * accI[0];
        const float p1 = accR[1] * accR[1] + accI[1] * accI[1];
        const float p2 = accR[2] * accR[2] + accI[2] * accI[2];
        const float p3 = accR[3] * accR[3] + accI[3] * accI[3];

        float mx = fmaxf(fmaxf(p0, p1), fmaxf(p2, p3));
        mx = fmaxf(mx, __shfl_xor(mx, 16));
        mx = fmaxf(mx, __shfl_xor(mx, 32));
        const float inv = 1.0f / mx;

        const float4 o = make_float4(p0 * inv, p1 * inv, p2 * inv, p3 * inv);
        *(float4*)(out + (size_t)b * 64 + g * 16 + quad * 4) = o;
    }
}

extern "C" void kernel_launch(void* const* d_in, const int* in_sizes, int n_in,
                              void* d_out, int out_size, void* d_ws, size_t ws_size,
                              hipStream_t stream) {
    const float* x = (const float*)d_in[0];   // [B, 5]
    const float* w = (const float*)d_in[1];   // [4, 4, 5, 3]
    float* out = (float*)d_out;               // [B, 64]
    const int B = in_sizes[0] / NQ;           // 65536

    // 512 blocks of (128 batches x 4 g); 2 blocks/CU.
    pqg_fused<<<B / 128, 256, 0, stream>>>(x, w, out);
}

// Round 8
// 68.978 us; speedup vs baseline: 1.0951x; 1.0951x over previous
//
#include <hip/hip_runtime.h>

// PatchQuantumGenerator, round 8: register-resident M build (bisected).
// Wave = one generator g x 128 batches. Lane (cg=lane>>4, m=lane&15) owns
// row m, cols cg*8+j of M (16x32 complex) in registers == f16 A-frag layout.
// vs r7 (failed 0.25): CNOT uses DIRECT per-column sigma (no linearity
// trick); cross-lane Rot gates (q=0,1) go through LDS scratch reading BOTH
// pair columns with the full formula (no __shfl_xor, no role-coefficients).
// Lane-local gates q=2,3,4 stay in registers. Zero __syncthreads.

#define NGEN 4
#define NLAY 4
#define NQ   5

typedef _Float16 half8 __attribute__((ext_vector_type(8)));
typedef float    f32x4 __attribute__((ext_vector_type(4)));

// In-wave LDS ordering (validated r6): drain DS ops, forbid reordering.
#define WAVE_SYNC()                                                  \
    do {                                                             \
        __builtin_amdgcn_wave_barrier();                             \
        asm volatile("s_waitcnt lgkmcnt(0)" ::: "memory");           \
        __builtin_amdgcn_wave_barrier();                             \
    } while (0)

__global__ __launch_bounds__(256) void pqg_fused(
    const float* __restrict__ x,      // [B,5]
    const float* __restrict__ wts,    // [4,4,5,3]
    float* __restrict__ out)          // [B,64]
{
    __shared__ float  gm[NGEN][NLAY * NQ * 8];   // gate matrices, per wave
    __shared__ float2 cs[NGEN][16 * 33];         // exchange scratch, per wave
    __shared__ float  scS[NGEN][640];            // sincos, per wave
    __shared__ float  scC[NGEN][640];

    const int t    = threadIdx.x;
    const int lane = t & 63;
    const int g    = t >> 6;              // wave index == generator
    const int b0   = blockIdx.x * 128;
    const int cg   = lane >> 4;           // col group (0..3)
    const int m    = lane & 15;           // row

    // ---- Gate matrices for this wave's g (lanes 0..19).
    // Rot = RZ(omega) RY(theta) RZ(phi); verified r1-r6.
    if (lane < NLAY * NQ) {
        const float* wp = wts + (g * (NLAY * NQ) + lane) * 3;
        const float phi = wp[0], theta = wp[1], omega = wp[2];
        const float a = 0.5f * (phi + omega);
        const float bb = 0.5f * (phi - omega);
        const float h = 0.5f * theta;
        const float sa = __sinf(a), ca = __cosf(a);
        const float sb = __sinf(bb), cb = __cosf(bb);
        const float st = __sinf(h), ct = __cosf(h);
        float* mm = &gm[g][lane * 8];
        mm[0] =  ca * ct;  mm[1] = -sa * ct;   // u00
        mm[2] = -cb * st;  mm[3] = -sb * st;   // u01
        mm[4] =  cb * st;  mm[5] = -sb * st;   // u10
        mm[6] =  ca * ct;  mm[7] =  sa * ct;   // u11
    }

    // ---- Sincos staging, wave-local (128 batches = 640 pairs).
#pragma unroll
    for (int e = 0; e < 10; ++e) {
        const int idx = e * 64 + lane;                  // 0..639
        const float tt = 0.5f * x[(size_t)b0 * 5 + idx];
        scS[g][idx] = __sinf(tt);
        scC[g][idx] = __cosf(tt);
    }
    WAVE_SYNC();   // gm + sincos visible within the wave

    // ---- M init: M = P (rows 0..15 of identity). Lane holds cols cg*8+j.
    float mr[8], mi[8];
#pragma unroll
    for (int j = 0; j < 8; ++j) {
        mr[j] = (cg * 8 + j == m) ? 1.0f : 0.0f;
        mi[j] = 0.0f;
    }

    // ---- Build M = P*U, gates in REVERSE circuit order (algebra = r5/r6).
#pragma unroll
    for (int l = NLAY - 1; l >= 0; --l) {
        // CNOT group: new[.,c] = old[.,sigma_l(c)], sigma = ascending q
        // conditional-XOR chain (exact r5 formulation, per column).
#pragma unroll
        for (int j = 0; j < 8; ++j)
            cs[g][m * 33 + cg * 8 + j] = make_float2(mr[j], mi[j]);
        WAVE_SYNC();
        {
            float2 tmp[8];
#pragma unroll
            for (int j = 0; j < 8; ++j) {
                int v = cg * 8 + j;
#pragma unroll
                for (int q = 0; q < NQ; ++q) {
                    const int cb = 16 >> q;
                    int tq = q + l + 1; if (tq >= NQ) tq -= NQ;
                    const int tb = 16 >> tq;
                    if (v & cb) v ^= tb;
                }
                tmp[j] = cs[g][m * 33 + v];
            }
            WAVE_SYNC();
#pragma unroll
            for (int j = 0; j < 8; ++j) { mr[j] = tmp[j].x; mi[j] = tmp[j].y; }
        }

        // Rot gates reverse order q=4,3,2: lane-local register pairs.
#pragma unroll
        for (int q = NQ - 1; q >= 2; --q) {
            const float4 u0 = *(const float4*)&gm[g][(l * NQ + q) * 8];
            const float4 u1 = *(const float4*)&gm[g][(l * NQ + q) * 8 + 4];
            const float u00r = u0.x, u00i = u0.y, u01r = u0.z, u01i = u0.w;
            const float u10r = u1.x, u10i = u1.y, u11r = u1.z, u11i = u1.w;
            const int sb = 16 >> q;   // 1,2,4
#pragma unroll
            for (int ja = 0; ja < 8; ++ja) {
                if (!(ja & sb)) {
                    const int jb = ja | sb;
                    const float ar = mr[ja], ai = mi[ja];
                    const float br = mr[jb], bi = mi[jb];
                    // right-mult: col_i <- u00*ci + u10*cj ; col_j <- u01*ci + u11*cj
                    mr[ja] = u00r * ar - u00i * ai + u10r * br - u10i * bi;
                    mi[ja] = u00r * ai + u00i * ar + u10r * bi + u10i * br;
                    mr[jb] = u01r * ar - u01i * ai + u11r * br - u11i * bi;
                    mi[jb] = u01r * ai + u01i * ar + u11r * bi + u11i * br;
                }
            }
        }

        // Rot gates q=1,0: cross-group pairs via LDS, full two-term formula.
#pragma unroll
        for (int q = 1; q >= 0; --q) {
            const float4 u0 = *(const float4*)&gm[g][(l * NQ + q) * 8];
            const float4 u1 = *(const float4*)&gm[g][(l * NQ + q) * 8 + 4];
            const float u00r = u0.x, u00i = u0.y, u01r = u0.z, u01i = u0.w;
            const float u10r = u1.x, u10i = u1.y, u11r = u1.z, u11i = u1.w;
            const int sb = 16 >> q;   // 8 or 16
#pragma unroll
            for (int j = 0; j < 8; ++j)
                cs[g][m * 33 + cg * 8 + j] = make_float2(mr[j], mi[j]);
            WAVE_SYNC();
            // column c = cg*8+j; i = c&~sb, jcol = c|sb (sb>=8 so j bits free)
            const int ibase = (cg * 8) & ~sb;
            const int jbase = (cg * 8) |  sb;
            const bool hi = ((cg * 8) & sb) != 0;   // my cols have gate-bit 1
            const float k0r = hi ? u01r : u00r, k0i = hi ? u01i : u00i;
            const float k1r = hi ? u11r : u10r, k1i = hi ? u11i : u10i;
#pragma unroll
            for (int j = 0; j < 8; ++j) {
                const float2 A2 = cs[g][m * 33 + ibase + j];   // col_i (bit 0)
                const float2 B2 = cs[g][m * 33 + jbase + j];   // col_j (bit 1)
                // new_c = bit0: u00*A + u10*B ; bit1: u01*A + u11*B
                mr[j] = k0r * A2.x - k0i * A2.y + k1r * B2.x - k1i * B2.y;
                mi[j] = k0r * A2.y + k0i * A2.x + k1r * B2.y + k1i * B2.x;
            }
            WAVE_SYNC();
        }
    }

    // ---- A-fragments: ownership already matches f16 A-frag layout.
    half8 Ar, Ai;
#pragma unroll
    for (int j = 0; j < 8; ++j) {
        Ar[j] = (_Float16)mr[j];
        Ai[j] = (_Float16)mi[j];
    }

    // ---- GEMM: 8 tiles x 16 batches = 128 batches for this wave's g.
    const int quad = cg;
    const int n    = m;

#pragma unroll
    for (int t8 = 0; t8 < 8; ++t8) {
        const int bl = t8 * 16 + n;
        const int b  = b0 + bl;
        const float* C = &scC[g][bl * 5];
        const float* S = &scS[g][bl * 5];

        // B-frag bit-map (verified r2): k=quad*8+j; quad&2->q0, quad&1->q1,
        // j&4->q2, j&2->q3, j&1->q4.
        const float f01 = ((quad & 2) ? S[0] : C[0]) * ((quad & 1) ? S[1] : C[1]);
        const float a0 = f01 * C[2], a1 = f01 * S[2];
        const float b00 = a0 * C[3], b01 = a0 * S[3];
        const float b10 = a1 * C[3], b11 = a1 * S[3];

        half8 Bf;
        Bf[0] = (_Float16)(b00 * C[4]);  Bf[1] = (_Float16)(b00 * S[4]);
        Bf[2] = (_Float16)(b01 * C[4]);  Bf[3] = (_Float16)(b01 * S[4]);
        Bf[4] = (_Float16)(b10 * C[4]);  Bf[5] = (_Float16)(b10 * S[4]);
        Bf[6] = (_Float16)(b11 * C[4]);  Bf[7] = (_Float16)(b11 * S[4]);

        f32x4 accR = {0.f, 0.f, 0.f, 0.f};
        f32x4 accI = {0.f, 0.f, 0.f, 0.f};
        accR = __builtin_amdgcn_mfma_f32_16x16x32_f16(Ar, Bf, accR, 0, 0, 0);
        accI = __builtin_amdgcn_mfma_f32_16x16x32_f16(Ai, Bf, accI, 0, 0, 0);

        // C/D: col = lane&15 (batch), row = quad*4 + reg (output k).
        const float p0 = accR[0] * accR[0] + accI[0] * accI[0];
        const float p1 = accR[1] * accR[1] + accI[1] * accI[1];
        const float p2 = accR[2] * accR[2] + accI[2] * accI[2];
        const float p3 = accR[3] * accR[3] + accI[3] * accI[3];

        float mx = fmaxf(fmaxf(p0, p1), fmaxf(p2, p3));
        mx = fmaxf(mx, __shfl_xor(mx, 16));
        mx = fmaxf(mx, __shfl_xor(mx, 32));
        const float inv = 1.0f / mx;

        const float4 o = make_float4(p0 * inv, p1 * inv, p2 * inv, p3 * inv);
        *(float4*)(out + (size_t)b * 64 + g * 16 + quad * 4) = o;
    }
}

extern "C" void kernel_launch(void* const* d_in, const int* in_sizes, int n_in,
                              void* d_out, int out_size, void* d_ws, size_t ws_size,
                              hipStream_t stream) {
    const float* x = (const float*)d_in[0];   // [B, 5]
    const float* w = (const float*)d_in[1];   // [4, 4, 5, 3]
    float* out = (float*)d_out;               // [B, 64]
    const int B = in_sizes[0] / NQ;           // 65536

    // 512 blocks of (128 batches x 4 independent waves, one per g).
    pqg_fused<<<B / 128, 256, 0, stream>>>(x, w, out);
}